// Round 8
// baseline (362.362 us; speedup 1.0000x reference)
//
#include <hip/hip_runtime.h>
#include <hip/hip_bf16.h>
#include <stdint.h>

#define MDIM 4096
#define NDIM 4096
#define KDIM 4096

typedef float f32x4 __attribute__((ext_vector_type(4)));
typedef __bf16 bf16x8 __attribute__((ext_vector_type(8)));
typedef short s16x8 __attribute__((ext_vector_type(8)));

// Packed fragment-order layout for a 4096x4096 bf16 operand P[row][k]:
//   band b = row>>7, ktile t = k>>5, frag f = (row&127)>>4,
//   lane = ((k>>3)&3)*16 + (row&15), j = k&7
//   short index = ((((b*128 + t)*8 + f)*64) + lane)*8 + j
// One frag = 1KB contiguous => wave reads contiguous in global AND LDS.

__device__ __forceinline__ unsigned short f2bf(float x) {
  union { float f; unsigned u; } v; v.f = x;
  return (unsigned short)((v.u + 0x7fffu + ((v.u >> 16) & 1u)) >> 16);
}

// ---- HW packed bf16 atomic: global_atomic_pk_add_bf16 (fire-and-forget) ----
// Other half of the word gets +0.0 (bf16 0x0000): only flips -0.0 -> +0.0.
__device__ __forceinline__ void scat_one(unsigned short* __restrict__ Wpk,
                                         int m, int k, float val) {
  unsigned short bits = f2bf(val);
  size_t chunk = ((((size_t)(m >> 7) * 128 + (k >> 5)) * 8 + ((m >> 4) & 7)) * 64) +
                 (((k >> 3) & 3) * 16 + (m & 15));
  size_t idx = chunk * 8 + (k & 7);
  unsigned data = ((unsigned)bits) << ((unsigned)(idx & 1) * 16u);
  unsigned short* p = &Wpk[idx & ~(size_t)1];  // 4B-aligned
  asm volatile("global_atomic_pk_add_bf16 %0, %1, off" :: "v"(p), "v"(data) : "memory");
}

// ---- fused prep: blocks [0, scBlocks) scatter COO (4 nnz/thread); rest pack x ----
__global__ __launch_bounds__(256) void prep_kernel(const int* __restrict__ rows,
                                                   const int* __restrict__ cols,
                                                   const float* __restrict__ vals, int nnz,
                                                   int scBlocks,
                                                   unsigned short* __restrict__ Wpk,
                                                   const float* __restrict__ x,
                                                   short* __restrict__ Xpk) {
  int b = blockIdx.x, tid = threadIdx.x;
  if (b < scBlocks) {
    int i0 = (b * 256 + tid) * 4;
    if (i0 >= nnz) return;
    if (i0 + 3 < nnz) {
      int4 r4 = *(const int4*)&rows[i0];
      int4 c4 = *(const int4*)&cols[i0];
      float4 v4 = *(const float4*)&vals[i0];
      scat_one(Wpk, r4.x, c4.x, v4.x);
      scat_one(Wpk, r4.y, c4.y, v4.y);
      scat_one(Wpk, r4.z, c4.z, v4.z);
      scat_one(Wpk, r4.w, c4.w, v4.w);
    } else {
      for (int u = 0; u < 4 && i0 + u < nnz; u++)
        scat_one(Wpk, rows[i0 + u], cols[i0 + u], vals[i0 + u]);
    }
  } else {
    __shared__ float tile[32 * 65];
    int pb = b - scBlocks;
    int n0 = (pb & 63) * 64, k0 = (pb >> 6) * 32;
#pragma unroll
    for (int r = 0; r < 8; r++) {
      int elem = r * 256 + tid;
      int kk = elem >> 6, nn = elem & 63;
      tile[kk * 65 + nn] = x[(size_t)(k0 + kk) * NDIM + n0 + nn];
    }
    __syncthreads();
    int region = tid >> 6, lane = tid & 63;
    int kh = lane >> 4, nl = region * 16 + (lane & 15);
    s16x8 v;
#pragma unroll
    for (int j = 0; j < 8; j++) v[j] = (short)f2bf(tile[(kh * 8 + j) * 65 + nl]);
    int f = ((n0 & 127) >> 4) + region;
    size_t chunk = (((size_t)(n0 >> 7) * 128 + (k0 >> 5)) * 8 + f) * 64 + lane;
    *(s16x8*)&Xpk[chunk * 8] = v;
  }
}

// ---- 256x256-tile 8-wave MFMA GEMM, 4-deep ring, m201 dual-barrier phases ----
// Per ktile (K=32), TWO phases, each the full m201 discipline:
//   { ds_reads (8 or 4) ; 2 stage gloads ; s_barrier ; lgkmcnt(0)+sched_barrier ;
//     setprio(1) 16 MFMA setprio(0) ; [vmcnt(8) in phase B] ; s_barrier }
// Reads are issued in the inter-barrier window so residual latency drains in the
// aligned lgkmcnt(0); both waves/SIMD then burst MFMA keeping the pipe saturated.
// vmcnt(8) once per ktile retires the oldest tile's 4 loads (never drains to 0).

#define GLOAD16(gp, lp)                                              \
  __builtin_amdgcn_global_load_lds(                                  \
      (const __attribute__((address_space(1))) void*)(gp),           \
      (__attribute__((address_space(3))) void*)(lp), 16, 0, 0)

__global__ __launch_bounds__(512, 2) void gemm_kernel(const short* __restrict__ A,
                                                      const short* __restrict__ Bt,
                                                      const float* __restrict__ bias,
                                                      float* __restrict__ C) {
  // 4 ring buffers x 16 chunks x 512 shorts (1KB) = 16KB per operand per buf;
  // total LDS = 2 * 4 * 16KB = 128KB -> 1 block/CU, 8 waves.
  __shared__ __align__(16) short sA[4][8192];
  __shared__ __align__(16) short sB[4][8192];

  int tid = threadIdx.x, lane = tid & 63, w = tid >> 6;
  int wr = w >> 2, wc = w & 3;              // 2 (M) x 4 (N) wave grid
  int m16 = lane & 15, quad = lane >> 4;
  int by = blockIdx.y, bx = blockIdx.x;

  f32x4 acc[8][4];
#pragma unroll
  for (int i = 0; i < 8; i++)
#pragma unroll
    for (int j = 0; j < 4; j++) acc[i][j] = f32x4{0.f, 0.f, 0.f, 0.f};

  // Staging: per K-tile (K=32) the A-tile is 16 chunks (band-half s=0/1, frag w).
  // Wave w stages chunk s*8+w of each operand; 4 gload_lds per thread per tile.
  const short* aSrc[2];
  const short* bSrc[2];
  int ldsOff[2];
#pragma unroll
  for (int s = 0; s < 2; s++) {
    aSrc[s] = A + ((size_t)(2 * by + s) * 128 * 8 + w) * 512 + lane * 8;
    bSrc[s] = Bt + ((size_t)(2 * bx + s) * 128 * 8 + w) * 512 + lane * 8;
    ldsOff[s] = (s * 8 + w) * 512 + lane * 8;
  }
  // K-tile stride in shorts: 8 frags * 512 = 4096.

  // Prologue: stage tiles 0,1,2 into bufs 0,1,2 (order A,A,B,B per tile —
  // the vmcnt ledger depends on 4 loads per tile in this issue order).
#pragma unroll
  for (int t = 0; t < 3; t++) {
    GLOAD16(aSrc[0] + (size_t)t * 4096, &sA[t][ldsOff[0]]);
    GLOAD16(aSrc[1] + (size_t)t * 4096, &sA[t][ldsOff[1]]);
    GLOAD16(bSrc[0] + (size_t)t * 4096, &sB[t][ldsOff[0]]);
    GLOAD16(bSrc[1] + (size_t)t * 4096, &sB[t][ldsOff[1]]);
  }
  // Tile 0 resident before first ds_read: retire its 4 loads, keep 8 in flight.
  __builtin_amdgcn_s_waitcnt(0x0F78);  // vmcnt(8)
  __builtin_amdgcn_s_barrier();

  for (int t = 0; t < 128; t++) {
    int buf = t & 3;
    int nbuf = (t + 3) & 3;
    size_t tn = (size_t)((t + 3) & 127) * 4096;  // wrap prefetch stays in-bounds

    const short* pA = &sA[buf][0];
    const short* pB = &sB[buf][0];
    bf16x8 a[4], b[4], a2[4];

    // ---- phase A: reads + A-half stage, barrier, aligned MFMA cluster ----
#pragma unroll
    for (int mi = 0; mi < 4; mi++)
      a[mi] = *(const bf16x8*)&pA[(wr * 8 + mi) * 512 + lane * 8];
#pragma unroll
    for (int nj = 0; nj < 4; nj++)
      b[nj] = *(const bf16x8*)&pB[((wc >> 1) * 8 + (wc & 1) * 4 + nj) * 512 + lane * 8];
    // stage A-half of tile t+3 into buf (t-1)&3 (readers drained their ds_reads
    // via lgkmcnt(0) before iter t-1's final barrier, which precedes this issue)
    GLOAD16(aSrc[0] + tn, &sA[nbuf][ldsOff[0]]);
    GLOAD16(aSrc[1] + tn, &sA[nbuf][ldsOff[1]]);
    __builtin_amdgcn_s_barrier();
    __builtin_amdgcn_s_waitcnt(0xC07F);  // lgkmcnt(0): this phase's reads resident
    __builtin_amdgcn_sched_barrier(0);
    __builtin_amdgcn_s_setprio(1);
#pragma unroll
    for (int mi = 0; mi < 4; mi++)
#pragma unroll
      for (int nj = 0; nj < 4; nj++)
        acc[mi][nj] = __builtin_amdgcn_mfma_f32_16x16x32_bf16(a[mi], b[nj], acc[mi][nj], 0, 0, 0);
    __builtin_amdgcn_s_setprio(0);
    __builtin_amdgcn_s_barrier();

    // ---- phase B: a2 reads + B-half stage, barrier, aligned MFMA cluster ----
#pragma unroll
    for (int mi = 0; mi < 4; mi++)
      a2[mi] = *(const bf16x8*)&pA[(wr * 8 + 4 + mi) * 512 + lane * 8];
    GLOAD16(bSrc[0] + tn, &sB[nbuf][ldsOff[0]]);
    GLOAD16(bSrc[1] + tn, &sB[nbuf][ldsOff[1]]);
    __builtin_amdgcn_s_barrier();
    __builtin_amdgcn_s_waitcnt(0xC07F);  // lgkmcnt(0)
    __builtin_amdgcn_sched_barrier(0);
    __builtin_amdgcn_s_setprio(1);
#pragma unroll
    for (int mi = 0; mi < 4; mi++)
#pragma unroll
      for (int nj = 0; nj < 4; nj++)
        acc[4 + mi][nj] = __builtin_amdgcn_mfma_f32_16x16x32_bf16(a2[mi], b[nj], acc[4 + mi][nj], 0, 0, 0);
    __builtin_amdgcn_s_setprio(0);

    // retire tile t+1's 4 loads (oldest); 8 stay in flight — never drains to 0.
    __builtin_amdgcn_s_waitcnt(0x0F78);  // vmcnt(8)
    __builtin_amdgcn_s_barrier();
  }
  __builtin_amdgcn_s_waitcnt(0x0F70);  // vmcnt(0): drain wrap prefetch

  // Epilogue: C = acc + bias
#pragma unroll
  for (int nj = 0; nj < 4; nj++) {
    int col = bx * 256 + wc * 64 + nj * 16 + m16;
    float bv = bias[col];
#pragma unroll
    for (int mi = 0; mi < 8; mi++) {
      int row0 = by * 256 + wr * 128 + mi * 16 + quad * 4;
      f32x4 v = acc[mi][nj];
#pragma unroll
      for (int r = 0; r < 4; r++) C[(size_t)(row0 + r) * NDIM + col] = v[r] + bv;
    }
  }
}

extern "C" void kernel_launch(void* const* d_in, const int* in_sizes, int n_in,
                              void* d_out, int out_size, void* d_ws, size_t ws_size,
                              hipStream_t stream) {
  const float* x = (const float*)d_in[0];
  const int* rows = (const int*)d_in[1];
  const int* cols = (const int*)d_in[2];
  const float* vals = (const float*)d_in[3];
  const float* bias = (const float*)d_in[4];
  int nnz = in_sizes[1];
  float* y = (float*)d_out;

  char* ws = (char*)d_ws;
  unsigned short* Wpk = (unsigned short*)ws;
  short* Xpk = (short*)(ws + (32u << 20));

  int scBlocks = (nnz + 1023) / 1024;            // 4 nnz per thread
  int pxBlocks = (NDIM / 64) * (KDIM / 32);      // 8192

  hipMemsetAsync(Wpk, 0, (size_t)MDIM * KDIM * sizeof(short), stream);
  prep_kernel<<<scBlocks + pxBlocks, 256, 0, stream>>>(rows, cols, vals, nnz, scBlocks,
                                                       Wpk, x, Xpk);
  gemm_kernel<<<dim3(NDIM / 256, MDIM / 256), 512, 0, stream>>>((const short*)Wpk, Xpk, bias, y);
}

// Round 9
// 328.443 us; speedup vs baseline: 1.1033x; 1.1033x over previous
//
#include <hip/hip_runtime.h>
#include <hip/hip_bf16.h>
#include <stdint.h>

#define MDIM 4096
#define NDIM 4096
#define KDIM 4096

typedef float f32x4 __attribute__((ext_vector_type(4)));
typedef __bf16 bf16x8 __attribute__((ext_vector_type(8)));
typedef short s16x8 __attribute__((ext_vector_type(8)));

// Packed fragment-order layout for a 4096x4096 bf16 operand P[row][k]:
//   band b = row>>7, ktile t = k>>5, frag f = (row&127)>>4,
//   lane = ((k>>3)&3)*16 + (row&15), j = k&7
//   short index = ((((b*128 + t)*8 + f)*64) + lane)*8 + j
// One frag = 1KB contiguous => wave reads contiguous in global AND LDS.

__device__ __forceinline__ unsigned short f2bf(float x) {
  union { float f; unsigned u; } v; v.f = x;
  return (unsigned short)((v.u + 0x7fffu + ((v.u >> 16) & 1u)) >> 16);
}

// ---- HW packed bf16 atomic: global_atomic_pk_add_bf16 (fire-and-forget) ----
// Other half of the word gets +0.0 (bf16 0x0000): only flips -0.0 -> +0.0.
__device__ __forceinline__ void scat_one(unsigned short* __restrict__ Wpk,
                                         int m, int k, float val) {
  unsigned short bits = f2bf(val);
  size_t chunk = ((((size_t)(m >> 7) * 128 + (k >> 5)) * 8 + ((m >> 4) & 7)) * 64) +
                 (((k >> 3) & 3) * 16 + (m & 15));
  size_t idx = chunk * 8 + (k & 7);
  unsigned data = ((unsigned)bits) << ((unsigned)(idx & 1) * 16u);
  unsigned short* p = &Wpk[idx & ~(size_t)1];  // 4B-aligned
  asm volatile("global_atomic_pk_add_bf16 %0, %1, off" :: "v"(p), "v"(data) : "memory");
}

// ---- fused prep: blocks [0, scBlocks) scatter COO (4 nnz/thread); rest pack x ----
__global__ __launch_bounds__(256) void prep_kernel(const int* __restrict__ rows,
                                                   const int* __restrict__ cols,
                                                   const float* __restrict__ vals, int nnz,
                                                   int scBlocks,
                                                   unsigned short* __restrict__ Wpk,
                                                   const float* __restrict__ x,
                                                   short* __restrict__ Xpk) {
  int b = blockIdx.x, tid = threadIdx.x;
  if (b < scBlocks) {
    int i0 = (b * 256 + tid) * 4;
    if (i0 >= nnz) return;
    if (i0 + 3 < nnz) {
      int4 r4 = *(const int4*)&rows[i0];
      int4 c4 = *(const int4*)&cols[i0];
      float4 v4 = *(const float4*)&vals[i0];
      scat_one(Wpk, r4.x, c4.x, v4.x);
      scat_one(Wpk, r4.y, c4.y, v4.y);
      scat_one(Wpk, r4.z, c4.z, v4.z);
      scat_one(Wpk, r4.w, c4.w, v4.w);
    } else {
      for (int u = 0; u < 4 && i0 + u < nnz; u++)
        scat_one(Wpk, rows[i0 + u], cols[i0 + u], vals[i0 + u]);
    }
  } else {
    __shared__ float tile[32 * 65];
    int pb = b - scBlocks;
    int n0 = (pb & 63) * 64, k0 = (pb >> 6) * 32;
#pragma unroll
    for (int r = 0; r < 8; r++) {
      int elem = r * 256 + tid;
      int kk = elem >> 6, nn = elem & 63;
      tile[kk * 65 + nn] = x[(size_t)(k0 + kk) * NDIM + n0 + nn];
    }
    __syncthreads();
    int region = tid >> 6, lane = tid & 63;
    int kh = lane >> 4, nl = region * 16 + (lane & 15);
    s16x8 v;
#pragma unroll
    for (int j = 0; j < 8; j++) v[j] = (short)f2bf(tile[(kh * 8 + j) * 65 + nl]);
    int f = ((n0 & 127) >> 4) + region;
    size_t chunk = (((size_t)(n0 >> 7) * 128 + (k0 >> 5)) * 8 + f) * 64 + lane;
    *(s16x8*)&Xpk[chunk * 8] = v;
  }
}

// ---- 256x256-tile 8-wave GEMM, 4-deep ring, cross-tile MFMA/ds_read interleave ----
// Model (R8 post-mortem): per ktile per CU, ds_read time (~1150cy on the CU-shared
// LDS port) and MFMA time (~1240cy) were fully SERIALIZED because in-order waves
// batch all reads before the MFMA burst. Fix: read tile t+1's a/b operands (8 reads)
// interleaved INSIDE tile t's MFMA stream, and tile t's a2 (4 reads) inside cluster
// 1, pinned 1:1 with sched_group_barrier (AITER pattern). Residency: vmcnt(4) at
// iter end => tiles t AND t+1 resident at iter start (4 in flight, never drains).
// Reuse hazard: buf (t+1)&3 overwritten at iter t+2's stage — two barriers after
// its last read (iter t group2 / iter t+1 group1). 0 bank conflicts (packed frags).

#define GLOAD16(gp, lp)                                              \
  __builtin_amdgcn_global_load_lds(                                  \
      (const __attribute__((address_space(1))) void*)(gp),           \
      (__attribute__((address_space(3))) void*)(lp), 16, 0, 0)

#define SGB __builtin_amdgcn_sched_group_barrier

__global__ __launch_bounds__(512, 2) void gemm_kernel(const short* __restrict__ A,
                                                      const short* __restrict__ Bt,
                                                      const float* __restrict__ bias,
                                                      float* __restrict__ C) {
  __shared__ __align__(16) short sA[4][8192];
  __shared__ __align__(16) short sB[4][8192];

  int tid = threadIdx.x, lane = tid & 63, w = tid >> 6;
  int wr = w >> 2, wc = w & 3;              // 2 (M) x 4 (N) wave grid
  int m16 = lane & 15, quad = lane >> 4;
  int by = blockIdx.y, bx = blockIdx.x;

  f32x4 acc[8][4];
#pragma unroll
  for (int i = 0; i < 8; i++)
#pragma unroll
    for (int j = 0; j < 4; j++) acc[i][j] = f32x4{0.f, 0.f, 0.f, 0.f};

  const short* aSrc[2];
  const short* bSrc[2];
  int ldsOff[2];
#pragma unroll
  for (int s = 0; s < 2; s++) {
    aSrc[s] = A + ((size_t)(2 * by + s) * 128 * 8 + w) * 512 + lane * 8;
    bSrc[s] = Bt + ((size_t)(2 * bx + s) * 128 * 8 + w) * 512 + lane * 8;
    ldsOff[s] = (s * 8 + w) * 512 + lane * 8;
  }
  int aOff = wr * 8 * 512 + lane * 8;                                   // lds a-frag base
  int bOff = ((wc >> 1) * 8 + (wc & 1) * 4) * 512 + lane * 8;           // lds b-frag base

  // Prologue: stage tiles 0,1,2 (order A,A,B,B per tile).
#pragma unroll
  for (int t = 0; t < 3; t++) {
    GLOAD16(aSrc[0] + (size_t)t * 4096, &sA[t][ldsOff[0]]);
    GLOAD16(aSrc[1] + (size_t)t * 4096, &sA[t][ldsOff[1]]);
    GLOAD16(bSrc[0] + (size_t)t * 4096, &sB[t][ldsOff[0]]);
    GLOAD16(bSrc[1] + (size_t)t * 4096, &sB[t][ldsOff[1]]);
  }
  __builtin_amdgcn_s_waitcnt(0x0F78);  // vmcnt(8): tile0 own-loads retired
  __builtin_amdgcn_s_barrier();        // tile0 resident

  bf16x8 aX[4], bX[4], aY[4], bY[4], a2[4];
#pragma unroll
  for (int mi = 0; mi < 4; mi++) aX[mi] = *(const bf16x8*)&sA[0][aOff + mi * 512];
#pragma unroll
  for (int nj = 0; nj < 4; nj++) bX[nj] = *(const bf16x8*)&sB[0][bOff + nj * 512];
  __builtin_amdgcn_s_waitcnt(0x0F74);  // vmcnt(4): tile1 own-loads retired
  __builtin_amdgcn_s_barrier();        // tile1 resident

  // Per-iter body. AC/BC = tile t regs (MFMA'd now); AN/BN = tile t+1 (read now).
#define K_ITER(T, AC, BC, AN, BN)                                                     \
  {                                                                                   \
    int t_ = (T);                                                                     \
    const short* pA = &sA[t_ & 3][0];                                                 \
    const short* pAn = &sA[(t_ + 1) & 3][0];                                          \
    const short* pBn = &sB[(t_ + 1) & 3][0];                                          \
    int nbuf_ = (t_ + 3) & 3;                                                         \
    size_t tn_ = (size_t)((t_ + 3) & 127) * 4096;                                     \
    GLOAD16(aSrc[0] + tn_, &sA[nbuf_][ldsOff[0]]);                                    \
    GLOAD16(aSrc[1] + tn_, &sA[nbuf_][ldsOff[1]]);                                    \
    /* group 1: 16 MFMA (AC x BC) interleaved with 4 a2 reads (tile t) */             \
    __builtin_amdgcn_s_setprio(1);                                                    \
    _Pragma("unroll") for (int mi = 0; mi < 4; mi++)                                  \
        a2[mi] = *(const bf16x8*)&pA[aOff + (4 + mi) * 512];                          \
    _Pragma("unroll") for (int mi = 0; mi < 4; mi++)                                  \
        _Pragma("unroll") for (int nj = 0; nj < 4; nj++)                              \
            acc[mi][nj] =                                                             \
        __builtin_amdgcn_mfma_f32_16x16x32_bf16(AC[mi], BC[nj], acc[mi][nj], 0, 0, 0);\
    SGB(0x8, 2, 0); SGB(0x100, 1, 0); SGB(0x8, 2, 0); SGB(0x100, 1, 0);               \
    SGB(0x8, 2, 0); SGB(0x100, 1, 0); SGB(0x8, 2, 0); SGB(0x100, 1, 0);               \
    SGB(0x8, 8, 0);                                                                   \
    __builtin_amdgcn_s_setprio(0);                                                    \
    GLOAD16(bSrc[0] + tn_, &sB[nbuf_][ldsOff[0]]);                                    \
    GLOAD16(bSrc[1] + tn_, &sB[nbuf_][ldsOff[1]]);                                    \
    /* group 2: 16 MFMA (a2 x BC) interleaved with 8 reads of tile t+1 (AN,BN) */     \
    __builtin_amdgcn_s_setprio(1);                                                    \
    _Pragma("unroll") for (int mi = 0; mi < 4; mi++)                                  \
        AN[mi] = *(const bf16x8*)&pAn[aOff + mi * 512];                               \
    _Pragma("unroll") for (int nj = 0; nj < 4; nj++)                                  \
        BN[nj] = *(const bf16x8*)&pBn[bOff + nj * 512];                               \
    _Pragma("unroll") for (int mi = 0; mi < 4; mi++)                                  \
        _Pragma("unroll") for (int nj = 0; nj < 4; nj++)                              \
            acc[4 + mi][nj] =                                                         \
        __builtin_amdgcn_mfma_f32_16x16x32_bf16(a2[mi], BC[nj], acc[4 + mi][nj], 0, 0, 0);\
    SGB(0x8, 1, 0); SGB(0x100, 1, 0); SGB(0x8, 1, 0); SGB(0x100, 1, 0);               \
    SGB(0x8, 1, 0); SGB(0x100, 1, 0); SGB(0x8, 1, 0); SGB(0x100, 1, 0);               \
    SGB(0x8, 1, 0); SGB(0x100, 1, 0); SGB(0x8, 1, 0); SGB(0x100, 1, 0);               \
    SGB(0x8, 1, 0); SGB(0x100, 1, 0); SGB(0x8, 1, 0); SGB(0x100, 1, 0);               \
    SGB(0x8, 8, 0);                                                                   \
    __builtin_amdgcn_s_setprio(0);                                                    \
    /* retire tile t+2's 4 loads; keep tile t+3's 4 in flight (never drains) */       \
    __builtin_amdgcn_s_waitcnt(0x0F74);  /* vmcnt(4) */                               \
    __builtin_amdgcn_s_barrier();        /* tiles t+1 (already) & t+2 resident */     \
  }

  for (int u = 0; u < 64; u++) {
    K_ITER(2 * u, aX, bX, aY, bY)
    K_ITER(2 * u + 1, aY, bY, aX, bX)
  }
#undef K_ITER
  __builtin_amdgcn_s_waitcnt(0x0F70);  // vmcnt(0): drain wrap prefetch

  // Epilogue: C = acc + bias
#pragma unroll
  for (int nj = 0; nj < 4; nj++) {
    int col = bx * 256 + wc * 64 + nj * 16 + m16;
    float bv = bias[col];
#pragma unroll
    for (int mi = 0; mi < 8; mi++) {
      int row0 = by * 256 + wr * 128 + mi * 16 + quad * 4;
      f32x4 v = acc[mi][nj];
#pragma unroll
      for (int r = 0; r < 4; r++) C[(size_t)(row0 + r) * NDIM + col] = v[r] + bv;
    }
  }
}

extern "C" void kernel_launch(void* const* d_in, const int* in_sizes, int n_in,
                              void* d_out, int out_size, void* d_ws, size_t ws_size,
                              hipStream_t stream) {
  const float* x = (const float*)d_in[0];
  const int* rows = (const int*)d_in[1];
  const int* cols = (const int*)d_in[2];
  const float* vals = (const float*)d_in[3];
  const float* bias = (const float*)d_in[4];
  int nnz = in_sizes[1];
  float* y = (float*)d_out;

  char* ws = (char*)d_ws;
  unsigned short* Wpk = (unsigned short*)ws;
  short* Xpk = (short*)(ws + (32u << 20));

  int scBlocks = (nnz + 1023) / 1024;            // 4 nnz per thread
  int pxBlocks = (NDIM / 64) * (KDIM / 32);      // 8192

  hipMemsetAsync(Wpk, 0, (size_t)MDIM * KDIM * sizeof(short), stream);
  prep_kernel<<<scBlocks + pxBlocks, 256, 0, stream>>>(rows, cols, vals, nnz, scBlocks,
                                                       Wpk, x, Xpk);
  gemm_kernel<<<dim3(NDIM / 256, MDIM / 256), 512, 0, stream>>>((const short*)Wpk, Xpk, bias, y);
}